// Round 3
// baseline (1350.293 us; speedup 1.0000x reference)
//
#include <hip/hip_runtime.h>
#include <cstdint>

#define N_NODES 50000
#define N_EDGES 1200000

// ---------- helpers: monotonic float<->uint map for atomicMax on floats ----------
__device__ __forceinline__ unsigned f2ord(float f) {
    unsigned b = __float_as_uint(f);
    return (b & 0x80000000u) ? ~b : (b | 0x80000000u);
}
__device__ __forceinline__ float ord2f(unsigned u) {
    unsigned b = (u & 0x80000000u) ? (u ^ 0x80000000u) : ~u;
    return __uint_as_float(b);
}

// ---------- GEMM: out[r, :128] = A[r, :128] @ W + b, four (W,b,O) per launch ----------
// block: 256 threads, tile 64 rows x 128 cols, K=128. W (64KB) stays L2-resident.
__global__ __launch_bounds__(256) void gemm4(
    const float* __restrict__ A, int nrows,
    const float* __restrict__ W0, const float* __restrict__ b0, float* __restrict__ O0,
    const float* __restrict__ W1, const float* __restrict__ b1, float* __restrict__ O1,
    const float* __restrict__ W2, const float* __restrict__ b2, float* __restrict__ O2,
    const float* __restrict__ W3, const float* __restrict__ b3, float* __restrict__ O3)
{
    const float* W; const float* bia; float* O;
    switch (blockIdx.y) {
        case 0:  W = W0; bia = b0; O = O0; break;
        case 1:  W = W1; bia = b1; O = O1; break;
        case 2:  W = W2; bia = b2; O = O2; break;
        default: W = W3; bia = b3; O = O3; break;
    }
    __shared__ float xs[64][128];
    const int t = threadIdx.x;
    const int row0 = blockIdx.x * 64;
    #pragma unroll
    for (int i = 0; i < 32; ++i) {
        int idx = t + i * 256;
        int r = idx >> 7, c = idx & 127;
        int gr = row0 + r;
        xs[r][c] = (gr < nrows) ? A[(size_t)gr * 128 + c] : 0.f;
    }
    __syncthreads();
    const int tx = t & 31, ty = t >> 5;
    float4 bb = *(const float4*)(bia + tx * 4);
    float acc[8][4];
    #pragma unroll
    for (int i = 0; i < 8; ++i) { acc[i][0] = bb.x; acc[i][1] = bb.y; acc[i][2] = bb.z; acc[i][3] = bb.w; }
    #pragma unroll 8
    for (int kk = 0; kk < 128; ++kk) {
        float4 w4 = *(const float4*)(W + kk * 128 + tx * 4);
        #pragma unroll
        for (int i = 0; i < 8; ++i) {
            float a = xs[ty * 8 + i][kk];
            acc[i][0] += a * w4.x; acc[i][1] += a * w4.y;
            acc[i][2] += a * w4.z; acc[i][3] += a * w4.w;
        }
    }
    #pragma unroll
    for (int i = 0; i < 8; ++i) {
        int gr = row0 + ty * 8 + i;
        if (gr < nrows) {
            float4 o; o.x = acc[i][0]; o.y = acc[i][1]; o.z = acc[i][2]; o.w = acc[i][3];
            *(float4*)(O + (size_t)gr * 128 + tx * 4) = o;
        }
    }
}

// ---------- per-(edge, group-of-16) attention logits ----------
// H==8: group == head, write alpha[e*8+h].  H==1: 8 groups reduce to one dot of 128.
template<int H>
__global__ __launch_bounds__(256) void edge_alpha(
    const float* __restrict__ q, const float* __restrict__ k,
    const int* __restrict__ src, const int* __restrict__ dst,
    float* __restrict__ alpha, float scale)
{
    int t = blockIdx.x * 256 + threadIdx.x;
    if (t >= N_EDGES * 8) return;
    int e = t >> 3, g = t & 7;
    int s = src[e], d = dst[e];
    const float4* qa = (const float4*)(q + (size_t)d * 128 + g * 16);
    const float4* ka = (const float4*)(k + (size_t)s * 128 + g * 16);
    float acc = 0.f;
    #pragma unroll
    for (int r = 0; r < 4; ++r) {
        float4 qv = qa[r], kv = ka[r];
        acc += qv.x * kv.x + qv.y * kv.y + qv.z * kv.z + qv.w * kv.w;
    }
    if (H == 8) {
        alpha[t] = acc * scale;
    } else {
        acc += __shfl_xor(acc, 1);
        acc += __shfl_xor(acc, 2);
        acc += __shfl_xor(acc, 4);
        if (g == 0) alpha[e] = acc * scale;
    }
}

template<int H>
__global__ __launch_bounds__(256) void seg_max_k(
    const float* __restrict__ alpha, const int* __restrict__ dst,
    unsigned* __restrict__ m)
{
    int t = blockIdx.x * 256 + threadIdx.x;
    if (t >= N_EDGES * H) return;
    int e = (H == 8) ? (t >> 3) : t;
    int h = (H == 8) ? (t & 7) : 0;
    atomicMax(&m[(size_t)dst[e] * H + h], f2ord(alpha[t]));
}

template<int H>
__global__ __launch_bounds__(256) void seg_sumexp_k(
    float* __restrict__ alpha, const int* __restrict__ dst,
    const unsigned* __restrict__ m, float* __restrict__ denom)
{
    int t = blockIdx.x * 256 + threadIdx.x;
    if (t >= N_EDGES * H) return;
    int e = (H == 8) ? (t >> 3) : t;
    int h = (H == 8) ? (t & 7) : 0;
    float mv = ord2f(m[(size_t)dst[e] * H + h]);
    float ea = expf(alpha[t] - mv);
    alpha[t] = ea;                       // overwrite logits with exp values
    atomicAdd(&denom[(size_t)dst[e] * H + h], ea);
}

// ---------- CSR build ----------
__global__ __launch_bounds__(256) void hist_k(const int* __restrict__ dst, int* __restrict__ deg)
{
    int e = blockIdx.x * 256 + threadIdx.x;
    if (e >= N_EDGES) return;
    atomicAdd(&deg[dst[e]], 1);
}

__global__ __launch_bounds__(1024) void scan_k(
    const int* __restrict__ deg, int* __restrict__ rowptr, int* __restrict__ cursor)
{
    __shared__ int part[1024];
    const int t = threadIdx.x;
    const int CH = (N_NODES + 1023) / 1024;  // 49
    int lo = t * CH, hi = min(lo + CH, N_NODES);
    int s = 0;
    for (int i = lo; i < hi; ++i) s += deg[i];
    part[t] = s;
    __syncthreads();
    for (int off = 1; off < 1024; off <<= 1) {
        int v2 = (t >= off) ? part[t - off] : 0;
        __syncthreads();
        part[t] += v2;
        __syncthreads();
    }
    int run = (t == 0) ? 0 : part[t - 1];
    for (int i = lo; i < hi; ++i) {
        rowptr[i] = run; cursor[i] = run;
        run += deg[i];
    }
}

__global__ __launch_bounds__(256) void fill_k(
    const int* __restrict__ src, const int* __restrict__ dst,
    int* __restrict__ cursor, int* __restrict__ eid, int* __restrict__ esrc)
{
    int e = blockIdx.x * 256 + threadIdx.x;
    if (e >= N_EDGES) return;
    int d = dst[e];
    int p = atomicAdd(&cursor[d], 1);
    eid[p] = e;
    esrc[p] = src[e];
}

// ---------- per-node aggregation (no atomics): out = (1/(den+eps)) * sum(ea * v[src]) + skip ----------
template<int H>
__global__ __launch_bounds__(128) void agg_k(
    const float* __restrict__ ea, const float* __restrict__ denom,
    const float* __restrict__ v, const float* __restrict__ skip,
    const int* __restrict__ rowptr, const int* __restrict__ deg,
    const int* __restrict__ eid, const int* __restrict__ esrc,
    float* __restrict__ out)
{
    const int n = blockIdx.x;
    const int c = threadIdx.x;                 // channel 0..127
    const int h = (H == 8) ? (c >> 4) : 0;
    float rd = 1.f / (denom[(size_t)n * H + h] + 1e-16f);
    int start = rowptr[n], cnt = deg[n];
    __shared__ int se[256];
    __shared__ int ss[256];
    float acc = 0.f;
    for (int base = 0; base < cnt; base += 256) {
        int mm = min(256, cnt - base);
        __syncthreads();
        for (int j = c; j < mm; j += 128) {
            se[j] = eid[start + base + j];
            ss[j] = esrc[start + base + j];
        }
        __syncthreads();
        for (int j = 0; j < mm; ++j) {
            acc += ea[(size_t)se[j] * H + h] * v[(size_t)ss[j] * 128 + c];
        }
    }
    out[(size_t)n * 128 + c] = acc * rd + skip[(size_t)n * 128 + c];
}

// ---------- launch ----------
extern "C" void kernel_launch(void* const* d_in, const int* in_sizes, int n_in,
                              void* d_out, int out_size, void* d_ws, size_t ws_size,
                              hipStream_t stream)
{
    const float* x    = (const float*)d_in[0];
    const int*   ei   = (const int*)d_in[1];
    const int*   esrc_in = ei;                 // edge_index[0] = src
    const int*   edst_in = ei + N_EDGES;       // edge_index[1] = dst

    const float* Wq1 = (const float*)d_in[2];  const float* bq1 = (const float*)d_in[3];
    const float* Wk1 = (const float*)d_in[4];  const float* bk1 = (const float*)d_in[5];
    const float* Wv1 = (const float*)d_in[6];  const float* bv1 = (const float*)d_in[7];
    const float* Ws1 = (const float*)d_in[8];  const float* bs1 = (const float*)d_in[9];
    const float* Wq2 = (const float*)d_in[10]; const float* bq2 = (const float*)d_in[11];
    const float* Wk2 = (const float*)d_in[12]; const float* bk2 = (const float*)d_in[13];
    const float* Wv2 = (const float*)d_in[14]; const float* bv2 = (const float*)d_in[15];
    const float* Ws2 = (const float*)d_in[16]; const float* bs2 = (const float*)d_in[17];

    float* out = (float*)d_out;

    // workspace layout (floats)
    const size_t NF = (size_t)N_NODES * 128;   // 6.4e6
    const size_t EH = (size_t)N_EDGES * 8;     // 9.6e6
    const size_t N8 = (size_t)N_NODES * 8;     // 4.0e5
    const size_t NP = 50048;                   // padded node count
    float* ws = (float*)d_ws;
    float*    Q    = ws;
    float*    K    = ws + NF;
    float*    V    = ws + 2 * NF;
    float*    S    = ws + 3 * NF;
    float*    EA   = ws + 4 * NF;                        // E*8 floats
    unsigned* M    = (unsigned*)(ws + 4 * NF + EH);      // N*8
    float*    DEN  = ws + 4 * NF + EH + N8;              // N*8
    int*      DEG  = (int*)(ws + 4 * NF + EH + 2 * N8);  // NP
    int*      ROW  = DEG + NP;
    int*      CUR  = ROW + NP;
    int*      EID  = CUR + NP;                           // E
    int*      ESRC = EID + N_EDGES;                      // E
    size_t needed = (4 * NF + EH + 2 * N8 + 3 * NP + 2 * (size_t)N_EDGES) * 4;
    if (ws_size < needed) return;  // workspace too small -> will fail validation visibly

    const int EB8 = (N_EDGES * 8 + 255) / 256;   // 37500
    const int EB1 = (N_EDGES + 255) / 256;       // 4688
    const int GR  = (N_NODES + 63) / 64;         // 782
    dim3 gemm_grid(GR, 4);

    // zero: M, DEN, DEG (contiguous)
    hipMemsetAsync(M, 0, (2 * N8 + NP) * 4, stream);

    // CSR (shared by both layers)
    hist_k<<<EB1, 256, 0, stream>>>(edst_in, DEG);
    scan_k<<<1, 1024, 0, stream>>>(DEG, ROW, CUR);
    fill_k<<<EB1, 256, 0, stream>>>(esrc_in, edst_in, CUR, EID, ESRC);

    // ---- layer 1: heads=8, ch=16 ----
    gemm4<<<gemm_grid, 256, 0, stream>>>(x, N_NODES,
        Wq1, bq1, Q,  Wk1, bk1, K,  Wv1, bv1, V,  Ws1, bs1, S);
    edge_alpha<8><<<EB8, 256, 0, stream>>>(Q, K, esrc_in, edst_in, EA, 0.25f);
    seg_max_k<8><<<EB8, 256, 0, stream>>>(EA, edst_in, M);
    seg_sumexp_k<8><<<EB8, 256, 0, stream>>>(EA, edst_in, M, DEN);
    agg_k<8><<<N_NODES, 128, 0, stream>>>(EA, DEN, V, S, ROW, DEG, EID, ESRC, out);  // out = h

    // ---- layer 2: heads=1, ch=128 ----
    gemm4<<<gemm_grid, 256, 0, stream>>>(out, N_NODES,
        Wq2, bq2, Q,  Wk2, bk2, K,  Wv2, bv2, V,  Ws2, bs2, S);
    hipMemsetAsync(M, 0, 2 * N8 * 4, stream);   // re-zero M, DEN
    edge_alpha<1><<<EB8, 256, 0, stream>>>(Q, K, esrc_in, edst_in, EA, 0.08838834764831845f);
    seg_max_k<1><<<EB1, 256, 0, stream>>>(EA, edst_in, M);
    seg_sumexp_k<1><<<EB1, 256, 0, stream>>>(EA, edst_in, M, DEN);
    agg_k<1><<<N_NODES, 128, 0, stream>>>(EA, DEN, V, S, ROW, DEG, EID, ESRC, out);
}

// Round 5
// 923.091 us; speedup vs baseline: 1.4628x; 1.4628x over previous
//
#include <hip/hip_runtime.h>
#include <cstdint>

#define N_NODES 50000
#define N_EDGES 1200000
#define NP 50048   // padded node count (>= N_NODES+1)

// ---------- GEMM: out[r, :128] = A[r, :128] @ W + b, four (W,b,O) per launch ----------
__global__ __launch_bounds__(256) void gemm4(
    const float* __restrict__ A, int nrows,
    const float* __restrict__ W0, const float* __restrict__ b0, float* __restrict__ O0,
    const float* __restrict__ W1, const float* __restrict__ b1, float* __restrict__ O1,
    const float* __restrict__ W2, const float* __restrict__ b2, float* __restrict__ O2,
    const float* __restrict__ W3, const float* __restrict__ b3, float* __restrict__ O3)
{
    const float* W; const float* bia; float* O;
    switch (blockIdx.y) {
        case 0:  W = W0; bia = b0; O = O0; break;
        case 1:  W = W1; bia = b1; O = O1; break;
        case 2:  W = W2; bia = b2; O = O2; break;
        default: W = W3; bia = b3; O = O3; break;
    }
    __shared__ float xs[64][128];
    const int t = threadIdx.x;
    const int row0 = blockIdx.x * 64;
    #pragma unroll
    for (int i = 0; i < 32; ++i) {
        int idx = t + i * 256;
        int r = idx >> 7, c = idx & 127;
        int gr = row0 + r;
        xs[r][c] = (gr < nrows) ? A[(size_t)gr * 128 + c] : 0.f;
    }
    __syncthreads();
    const int tx = t & 31, ty = t >> 5;
    float4 bb = *(const float4*)(bia + tx * 4);
    float acc[8][4];
    #pragma unroll
    for (int i = 0; i < 8; ++i) { acc[i][0] = bb.x; acc[i][1] = bb.y; acc[i][2] = bb.z; acc[i][3] = bb.w; }
    #pragma unroll 8
    for (int kk = 0; kk < 128; ++kk) {
        float4 w4 = *(const float4*)(W + kk * 128 + tx * 4);
        #pragma unroll
        for (int i = 0; i < 8; ++i) {
            float a = xs[ty * 8 + i][kk];
            acc[i][0] += a * w4.x; acc[i][1] += a * w4.y;
            acc[i][2] += a * w4.z; acc[i][3] += a * w4.w;
        }
    }
    #pragma unroll
    for (int i = 0; i < 8; ++i) {
        int gr = row0 + ty * 8 + i;
        if (gr < nrows) {
            float4 o; o.x = acc[i][0]; o.y = acc[i][1]; o.z = acc[i][2]; o.w = acc[i][3];
            *(float4*)(O + (size_t)gr * 128 + tx * 4) = o;
        }
    }
}

// ---------- CSR build ----------
__global__ __launch_bounds__(256) void hist_k(const int* __restrict__ dst, int* __restrict__ deg)
{
    int e = blockIdx.x * 256 + threadIdx.x;
    if (e >= N_EDGES) return;
    atomicAdd(&deg[dst[e]], 1);
}

__global__ __launch_bounds__(1024) void scan_k(
    const int* __restrict__ deg, int* __restrict__ rowptr, int* __restrict__ cursor)
{
    __shared__ int part[1024];
    const int t = threadIdx.x;
    const int CH = (N_NODES + 1023) / 1024;  // 49
    int lo = t * CH, hi = min(lo + CH, N_NODES);
    int s = 0;
    for (int i = lo; i < hi; ++i) s += deg[i];
    part[t] = s;
    __syncthreads();
    for (int off = 1; off < 1024; off <<= 1) {
        int v2 = (t >= off) ? part[t - off] : 0;
        __syncthreads();
        part[t] += v2;
        __syncthreads();
    }
    int run = (t == 0) ? 0 : part[t - 1];
    for (int i = lo; i < hi; ++i) {
        rowptr[i] = run; cursor[i] = run;
        run += deg[i];
    }
    if (t == 1023) rowptr[N_NODES] = part[1023];   // = E
}

__global__ __launch_bounds__(256) void fill_k(
    const int* __restrict__ src, const int* __restrict__ dst,
    int* __restrict__ cursor, int* __restrict__ esrc)
{
    int e = blockIdx.x * 256 + threadIdx.x;
    if (e >= N_EDGES) return;
    int p = atomicAdd(&cursor[dst[e]], 1);
    esrc[p] = src[e];
}

// ---------- fused edge+softmax+aggregate: one wave per node ----------
// Softmax without max-subtraction (shift-invariant; |alpha| ~ O(3) here, no overflow).
// Thread c of the node's wave owns channels {2c, 2c+1}. Per edge: gather k-row and
// v-row (float2, coalesced 512B/wave), in-wave shuffle-reduce dot, exp on all lanes,
// accumulate unnormalized sum and denom in registers. Normalize once at the end.
template<int H>
__global__ __launch_bounds__(256) void fused_attn(
    const float* __restrict__ Qm, const float* __restrict__ Km, const float* __restrict__ Vm,
    const float* __restrict__ Sm, const int* __restrict__ rowptr,
    const int* __restrict__ esrc, float* __restrict__ out, float scale)
{
    const int n = blockIdx.x * 4 + (threadIdx.x >> 6);   // 4 nodes per block, 1 wave each
    const int c = threadIdx.x & 63;                       // lane
    const int start = rowptr[n];
    const int cnt   = rowptr[n + 1] - start;
    float2 q2 = *(const float2*)(Qm + (size_t)n * 128 + 2 * c);
    q2.x *= scale; q2.y *= scale;
    float ax = 0.f, ay = 0.f, den = 0.f;
    for (int base = 0; base < cnt; base += 64) {
        int mm = min(64, cnt - base);
        int my_s = (c < mm) ? esrc[start + base + c] : 0;
        for (int j = 0; j < mm; ++j) {
            int s = __shfl(my_s, j);
            float2 k2 = *(const float2*)(Km + (size_t)s * 128 + 2 * c);
            float p = k2.x * q2.x + k2.y * q2.y;
            if (H == 8) {
                // head = (2c)>>4 = c>>3: reduce within 8-lane groups
                p += __shfl_xor(p, 1);
                p += __shfl_xor(p, 2);
                p += __shfl_xor(p, 4);
            } else {
                #pragma unroll
                for (int o = 1; o < 64; o <<= 1) p += __shfl_xor(p, o);
            }
            float ea = __expf(p);
            float2 v2 = *(const float2*)(Vm + (size_t)s * 128 + 2 * c);
            ax += ea * v2.x;
            ay += ea * v2.y;
            den += ea;
        }
    }
    float rd = 1.f / (den + 1e-16f);      // den==0 only when cnt==0 -> acc==0 -> out=skip
    float2 s2 = *(const float2*)(Sm + (size_t)n * 128 + 2 * c);
    float2 o2; o2.x = ax * rd + s2.x; o2.y = ay * rd + s2.y;
    *(float2*)(out + (size_t)n * 128 + 2 * c) = o2;
}

// ---------- launch ----------
extern "C" void kernel_launch(void* const* d_in, const int* in_sizes, int n_in,
                              void* d_out, int out_size, void* d_ws, size_t ws_size,
                              hipStream_t stream)
{
    const float* x       = (const float*)d_in[0];
    const int*   ei      = (const int*)d_in[1];
    const int*   esrc_in = ei;                 // edge_index[0] = src
    const int*   edst_in = ei + N_EDGES;       // edge_index[1] = dst

    const float* Wq1 = (const float*)d_in[2];  const float* bq1 = (const float*)d_in[3];
    const float* Wk1 = (const float*)d_in[4];  const float* bk1 = (const float*)d_in[5];
    const float* Wv1 = (const float*)d_in[6];  const float* bv1 = (const float*)d_in[7];
    const float* Ws1 = (const float*)d_in[8];  const float* bs1 = (const float*)d_in[9];
    const float* Wq2 = (const float*)d_in[10]; const float* bq2 = (const float*)d_in[11];
    const float* Wk2 = (const float*)d_in[12]; const float* bk2 = (const float*)d_in[13];
    const float* Wv2 = (const float*)d_in[14]; const float* bv2 = (const float*)d_in[15];
    const float* Ws2 = (const float*)d_in[16]; const float* bs2 = (const float*)d_in[17];

    float* out = (float*)d_out;

    // workspace layout (floats)
    const size_t NF = (size_t)N_NODES * 128;   // 6.4e6
    float* ws = (float*)d_ws;
    float* Q = ws;
    float* K = ws + NF;
    float* V = ws + 2 * NF;
    float* S = ws + 3 * NF;
    int*   DEG  = (int*)(ws + 4 * NF);         // NP
    int*   ROW  = DEG + NP;                    // NP (uses N_NODES+1)
    int*   CUR  = ROW + NP;                    // NP
    int*   ESRC = CUR + NP;                    // E
    size_t needed = (4 * NF + 3 * (size_t)NP + (size_t)N_EDGES) * 4;
    if (ws_size < needed) return;

    const int EB1 = (N_EDGES + 255) / 256;     // 4688
    const int GR  = (N_NODES + 63) / 64;       // 782
    dim3 gemm_grid(GR, 4);
    const int FB  = N_NODES / 4;               // 12500 blocks, 4 nodes each

    hipMemsetAsync(DEG, 0, NP * 4, stream);

    // CSR by destination (shared by both layers)
    hist_k<<<EB1, 256, 0, stream>>>(edst_in, DEG);
    scan_k<<<1, 1024, 0, stream>>>(DEG, ROW, CUR);
    fill_k<<<EB1, 256, 0, stream>>>(esrc_in, edst_in, CUR, ESRC);

    // ---- layer 1: heads=8, ch=16 ----
    gemm4<<<gemm_grid, 256, 0, stream>>>(x, N_NODES,
        Wq1, bq1, Q,  Wk1, bk1, K,  Wv1, bv1, V,  Ws1, bs1, S);
    fused_attn<8><<<FB, 256, 0, stream>>>(Q, K, V, S, ROW, ESRC, out, 0.25f);

    // ---- layer 2: heads=1, ch=128 ----
    gemm4<<<gemm_grid, 256, 0, stream>>>(out, N_NODES,
        Wq2, bq2, Q,  Wk2, bk2, K,  Wv2, bv2, V,  Ws2, bs2, S);
    fused_attn<1><<<FB, 256, 0, stream>>>(Q, K, V, S, ROW, ESRC, out, 0.08838834764831845f);
}

// Round 7
// 758.041 us; speedup vs baseline: 1.7813x; 1.2177x over previous
//
#include <hip/hip_runtime.h>
#include <cstdint>

#define N_NODES 50000
#define N_EDGES 1200000
#define NP2 50176          // padded node count, multiple of 256, >= N_NODES+1
#define NSCAN 196          // NP2/256

typedef __attribute__((ext_vector_type(8))) short short8;   // 8 bf16 in 4 VGPRs
typedef __attribute__((ext_vector_type(4))) float f32x4;

__device__ __forceinline__ unsigned short f2bf(float x) {
    unsigned u = __float_as_uint(x);
    unsigned r = (u + 0x7FFFu + ((u >> 16) & 1u)) >> 16;   // RNE
    return (unsigned short)r;
}
__device__ __forceinline__ float bf2f(unsigned short h) {
    return __uint_as_float(((unsigned)h) << 16);
}

// ---------- prep: W[k][n] fp32 -> WT_hi[n][k], WT_lo[n][k] bf16, 8 matrices ----------
__global__ __launch_bounds__(256) void prep_w(
    const float* __restrict__ W0, const float* __restrict__ W1,
    const float* __restrict__ W2, const float* __restrict__ W3,
    const float* __restrict__ W4, const float* __restrict__ W5,
    const float* __restrict__ W6, const float* __restrict__ W7,
    unsigned short* __restrict__ WTH, unsigned short* __restrict__ WTL)
{
    int g = blockIdx.x * 256 + threadIdx.x;          // 8*16384 threads
    int m = g >> 14, o = g & 16383;
    int n = o >> 7, k = o & 127;
    const float* W;
    switch (m) {
        case 0: W = W0; break; case 1: W = W1; break;
        case 2: W = W2; break; case 3: W = W3; break;
        case 4: W = W4; break; case 5: W = W5; break;
        case 6: W = W6; break; default: W = W7; break;
    }
    float x = W[k * 128 + n];
    unsigned short hi = f2bf(x);
    unsigned short lo = f2bf(x - bf2f(hi));
    WTH[g] = hi;
    WTL[g] = lo;
}

// ---------- GEMM via MFMA (hi/lo split): 4 outputs per launch ----------
// A fp32 [nrows][128]; WT[o][n][k] bf16 (hi & lo). Out: O0 f32, O1 bf16, O2 bf16, O3 f32.
// Block: 256 thr = 4 waves, BM=32 rows. wave w: rowgroup w>>1, output-pair w&1.
__global__ __launch_bounds__(256) void gemm_mfma(
    const float* __restrict__ A, int nrows,
    const unsigned short* __restrict__ WTH, const unsigned short* __restrict__ WTL,
    const float* __restrict__ b0, const float* __restrict__ b1,
    const float* __restrict__ b2, const float* __restrict__ b3,
    float* __restrict__ O0, unsigned short* __restrict__ O1,
    unsigned short* __restrict__ O2, float* __restrict__ O3)
{
    __shared__ unsigned short ah[32][136];   // +8 pad: 2-way-max bank aliasing (free)
    __shared__ unsigned short al[32][136];
    const int t = threadIdx.x;
    const int row0 = blockIdx.x * 32;

    // stage + split: 32x128 floats, thread t handles float4 idx {t, t+256, t+512, t+768}
    #pragma unroll
    for (int i = 0; i < 4; ++i) {
        int f4 = t + i * 256;
        int r = f4 >> 5, c4 = f4 & 31;
        int gr = row0 + r;
        float4 a4 = (gr < nrows) ? *(const float4*)(A + (size_t)gr * 128 + c4 * 4)
                                 : make_float4(0.f, 0.f, 0.f, 0.f);
        ushort4 h, l;
        h.x = f2bf(a4.x); l.x = f2bf(a4.x - bf2f(h.x));
        h.y = f2bf(a4.y); l.y = f2bf(a4.y - bf2f(h.y));
        h.z = f2bf(a4.z); l.z = f2bf(a4.z - bf2f(h.z));
        h.w = f2bf(a4.w); l.w = f2bf(a4.w - bf2f(h.w));
        *(ushort4*)&ah[r][c4 * 4] = h;
        *(ushort4*)&al[r][c4 * 4] = l;
    }
    __syncthreads();

    const int lane = t & 63;
    const int w    = t >> 6;
    const int rg   = w >> 1;        // row group (0/1)
    const int p    = w & 1;         // output pair: {0,1} or {2,3}
    const int mi   = lane & 15;
    const int kg   = lane >> 4;     // 0..3

    f32x4 acc[2][8] = {};

    #pragma unroll
    for (int ks = 0; ks < 4; ++ks) {
        short8 a_hi = *(const short8*)&ah[rg * 16 + mi][ks * 32 + kg * 8];
        short8 a_lo = *(const short8*)&al[rg * 16 + mi][ks * 32 + kg * 8];
        #pragma unroll
        for (int o = 0; o < 2; ++o) {
            const int out = p * 2 + o;
            const unsigned short* wh = WTH + out * 16384;
            const unsigned short* wl = WTL + out * 16384;
            #pragma unroll
            for (int ct = 0; ct < 8; ++ct) {
                size_t boff = (size_t)(ct * 16 + mi) * 128 + ks * 32 + kg * 8;
                short8 b_hi = *(const short8*)(wh + boff);
                short8 b_lo = *(const short8*)(wl + boff);
                acc[o][ct] = __builtin_amdgcn_mfma_f32_16x16x32_bf16(a_hi, b_hi, acc[o][ct], 0, 0, 0);
                acc[o][ct] = __builtin_amdgcn_mfma_f32_16x16x32_bf16(a_hi, b_lo, acc[o][ct], 0, 0, 0);
                acc[o][ct] = __builtin_amdgcn_mfma_f32_16x16x32_bf16(a_lo, b_hi, acc[o][ct], 0, 0, 0);
            }
        }
    }

    // epilogue: C[row = rg*16 + (lane>>4)*4 + r][col = ct*16 + (lane&15)] + bias
    const int g2 = lane >> 4;
    #pragma unroll
    for (int o = 0; o < 2; ++o) {
        const int out = p * 2 + o;
        const float* bptr = (out == 0) ? b0 : (out == 1) ? b1 : (out == 2) ? b2 : b3;
        #pragma unroll
        for (int ct = 0; ct < 8; ++ct) {
            int col = ct * 16 + mi;
            float bias_v = bptr[col];
            #pragma unroll
            for (int r = 0; r < 4; ++r) {
                int grow = row0 + rg * 16 + g2 * 4 + r;
                if (grow < nrows) {
                    float val = acc[o][ct][r] + bias_v;
                    size_t idx = (size_t)grow * 128 + col;
                    if (out == 0)      O0[idx] = val;
                    else if (out == 1) O1[idx] = f2bf(val);
                    else if (out == 2) O2[idx] = f2bf(val);
                    else               O3[idx] = val;
                }
            }
        }
    }
}

// ---------- CSR build ----------
__global__ __launch_bounds__(256) void hist_k(const int* __restrict__ dst, int* __restrict__ deg)
{
    int e = blockIdx.x * 256 + threadIdx.x;
    if (e >= N_EDGES) return;
    atomicAdd(&deg[dst[e]], 1);
}

__global__ __launch_bounds__(256) void scan1_k(const int* __restrict__ deg, int* __restrict__ bsum)
{
    __shared__ int s[256];
    int t = threadIdx.x;
    s[t] = deg[blockIdx.x * 256 + t];
    __syncthreads();
    for (int off = 128; off > 0; off >>= 1) {
        if (t < off) s[t] += s[t + off];
        __syncthreads();
    }
    if (t == 0) bsum[blockIdx.x] = s[0];
}

__global__ __launch_bounds__(256) void scan2_k(const int* __restrict__ bsum, int* __restrict__ boff,
                                               int* __restrict__ rowptr)
{
    __shared__ int s[256];
    int t = threadIdx.x;
    int v = (t < NSCAN) ? bsum[t] : 0;
    s[t] = v;
    __syncthreads();
    for (int off = 1; off < 256; off <<= 1) {
        int v2 = (t >= off) ? s[t - off] : 0;
        __syncthreads();
        s[t] += v2;
        __syncthreads();
    }
    if (t < NSCAN) boff[t] = s[t] - v;          // exclusive
    if (t == 0) rowptr[N_NODES] = N_EDGES;
}

__global__ __launch_bounds__(256) void scan3_k(const int* __restrict__ deg, const int* __restrict__ boff,
                                               int* __restrict__ rowptr, int* __restrict__ cursor)
{
    __shared__ int s[256];
    int t = threadIdx.x;
    int i = blockIdx.x * 256 + t;
    int d = deg[i];
    s[t] = d;
    __syncthreads();
    for (int off = 1; off < 256; off <<= 1) {
        int v2 = (t >= off) ? s[t - off] : 0;
        __syncthreads();
        s[t] += v2;
        __syncthreads();
    }
    if (i < N_NODES) {
        int val = boff[blockIdx.x] + s[t] - d;  // exclusive prefix
        rowptr[i] = val;
        cursor[i] = val;
    }
}

__global__ __launch_bounds__(256) void fill_k(
    const int* __restrict__ src, const int* __restrict__ dst,
    int* __restrict__ cursor, int* __restrict__ esrc)
{
    int e = blockIdx.x * 256 + threadIdx.x;
    if (e >= N_EDGES) return;
    int p = atomicAdd(&cursor[dst[e]], 1);
    esrc[p] = src[e];
}

// ---------- fused edge+softmax+aggregate: one wave per node, bf16 K/V gather ----------
template<int H>
__global__ __launch_bounds__(256) void fused_attn(
    const float* __restrict__ Qm, const unsigned short* __restrict__ Km,
    const unsigned short* __restrict__ Vm, const float* __restrict__ Sm,
    const int* __restrict__ rowptr, const int* __restrict__ esrc,
    float* __restrict__ out, float scale)
{
    const int n = blockIdx.x * 4 + (threadIdx.x >> 6);   // 4 nodes/block, 1 wave each
    const int c = threadIdx.x & 63;
    const int start = rowptr[n];
    const int cnt   = rowptr[n + 1] - start;
    float2 q2 = *(const float2*)(Qm + (size_t)n * 128 + 2 * c);
    q2.x *= scale; q2.y *= scale;
    float ax = 0.f, ay = 0.f, den = 0.f;
    for (int base = 0; base < cnt; base += 64) {
        int mm = min(64, cnt - base);
        int my_s = (c < mm) ? esrc[start + base + c] : 0;
        for (int j = 0; j < mm; ++j) {
            int s = __shfl(my_s, j);
            ushort2 kb = *(const ushort2*)(Km + (size_t)s * 128 + 2 * c);
            float p = bf2f(kb.x) * q2.x + bf2f(kb.y) * q2.y;
            if (H == 8) {
                p += __shfl_xor(p, 1);
                p += __shfl_xor(p, 2);
                p += __shfl_xor(p, 4);
            } else {
                #pragma unroll
                for (int o = 1; o < 64; o <<= 1) p += __shfl_xor(p, o);
            }
            float ea = __expf(p);
            ushort2 vb = *(const ushort2*)(Vm + (size_t)s * 128 + 2 * c);
            ax += ea * bf2f(vb.x);
            ay += ea * bf2f(vb.y);
            den += ea;
        }
    }
    float rd = 1.f / (den + 1e-16f);
    float2 s2 = *(const float2*)(Sm + (size_t)n * 128 + 2 * c);
    float2 o2; o2.x = ax * rd + s2.x; o2.y = ay * rd + s2.y;
    *(float2*)(out + (size_t)n * 128 + 2 * c) = o2;
}

// ---------- launch ----------
extern "C" void kernel_launch(void* const* d_in, const int* in_sizes, int n_in,
                              void* d_out, int out_size, void* d_ws, size_t ws_size,
                              hipStream_t stream)
{
    const float* x       = (const float*)d_in[0];
    const int*   ei      = (const int*)d_in[1];
    const int*   esrc_in = ei;                 // edge_index[0] = src
    const int*   edst_in = ei + N_EDGES;       // edge_index[1] = dst

    const float* Wq1 = (const float*)d_in[2];  const float* bq1 = (const float*)d_in[3];
    const float* Wk1 = (const float*)d_in[4];  const float* bk1 = (const float*)d_in[5];
    const float* Wv1 = (const float*)d_in[6];  const float* bv1 = (const float*)d_in[7];
    const float* Ws1 = (const float*)d_in[8];  const float* bs1 = (const float*)d_in[9];
    const float* Wq2 = (const float*)d_in[10]; const float* bq2 = (const float*)d_in[11];
    const float* Wk2 = (const float*)d_in[12]; const float* bk2 = (const float*)d_in[13];
    const float* Wv2 = (const float*)d_in[14]; const float* bv2 = (const float*)d_in[15];
    const float* Ws2 = (const float*)d_in[16]; const float* bs2 = (const float*)d_in[17];

    float* out = (float*)d_out;

    // workspace layout (bytes)
    char* base = (char*)d_ws;
    const size_t NF4 = (size_t)N_NODES * 128 * 4;   // 25.6 MB
    const size_t NF2 = (size_t)N_NODES * 128 * 2;   // 12.8 MB
    size_t off = 0;
    float*          Q    = (float*)(base + off);          off += NF4;
    float*          S    = (float*)(base + off);          off += NF4;
    unsigned short* Kb   = (unsigned short*)(base + off); off += NF2;
    unsigned short* Vb   = (unsigned short*)(base + off); off += NF2;
    unsigned short* WTH  = (unsigned short*)(base + off); off += 8 * 16384 * 2;
    unsigned short* WTL  = (unsigned short*)(base + off); off += 8 * 16384 * 2;
    int*            DEG  = (int*)(base + off);            off += (size_t)NP2 * 4;
    int*            ROW  = (int*)(base + off);            off += (size_t)NP2 * 4;
    int*            CUR  = (int*)(base + off);            off += (size_t)NP2 * 4;
    int*            BSUM = (int*)(base + off);            off += 1024;
    int*            BOFF = (int*)(base + off);            off += 1024;
    int*            ESRC = (int*)(base + off);            off += (size_t)N_EDGES * 4;
    if (ws_size < off) return;

    const int EB1 = (N_EDGES + 255) / 256;     // 4688
    const int GM  = (N_NODES + 31) / 32;       // 1563
    const int FB  = N_NODES / 4;               // 12500

    hipMemsetAsync(DEG, 0, (size_t)NP2 * 4, stream);

    // weight prep (both layers): order Q1,K1,V1,S1,Q2,K2,V2,S2
    prep_w<<<512, 256, 0, stream>>>(Wq1, Wk1, Wv1, Ws1, Wq2, Wk2, Wv2, Ws2, WTH, WTL);

    // CSR by destination (shared by both layers)
    hist_k<<<EB1, 256, 0, stream>>>(edst_in, DEG);
    scan1_k<<<NSCAN, 256, 0, stream>>>(DEG, BSUM);
    scan2_k<<<1, 256, 0, stream>>>(BSUM, BOFF, ROW);
    scan3_k<<<NSCAN, 256, 0, stream>>>(DEG, BOFF, ROW, CUR);
    fill_k<<<EB1, 256, 0, stream>>>(esrc_in, edst_in, CUR, ESRC);

    // ---- layer 1: heads=8, ch=16 ----
    gemm_mfma<<<GM, 256, 0, stream>>>(x, N_NODES, WTH, WTL,
        bq1, bk1, bv1, bs1, Q, Kb, Vb, S);
    fused_attn<8><<<FB, 256, 0, stream>>>(Q, Kb, Vb, S, ROW, ESRC, out, 0.25f);

    // ---- layer 2: heads=1, ch=128 ----
    gemm_mfma<<<GM, 256, 0, stream>>>(out, N_NODES, WTH + 4 * 16384, WTL + 4 * 16384,
        bq2, bk2, bv2, bs2, Q, Kb, Vb, S);
    fused_attn<1><<<FB, 256, 0, stream>>>(Q, Kb, Vb, S, ROW, ESRC, out, 0.08838834764831845f);
}

// Round 8
// 599.649 us; speedup vs baseline: 2.2518x; 1.2641x over previous
//
#include <hip/hip_runtime.h>
#include <cstdint>

#define N_NODES 50000
#define N_EDGES 1200000
#define NP2 50176          // padded node count, multiple of 256, >= N_NODES+1
#define NSCAN 196          // NP2/256
#define BM 64              // rows per GEMM block
#define GT 782             // row tiles = ceil(50000/64)
#define NWG 1564           // GT*2 output-pairs

typedef __attribute__((ext_vector_type(8))) short short8;   // 8 bf16 in 4 VGPRs
typedef __attribute__((ext_vector_type(4))) float f32x4;

__device__ __forceinline__ unsigned short f2bf(float x) {
    unsigned u = __float_as_uint(x);
    unsigned r = (u + 0x7FFFu + ((u >> 16) & 1u)) >> 16;   // RNE
    return (unsigned short)r;
}
__device__ __forceinline__ float bf2f(unsigned short h) {
    return __uint_as_float(((unsigned)h) << 16);
}
// LDS byte offset for [row][128 bf16] tiles with bank-conflict XOR swizzle (T2)
__device__ __forceinline__ int swz(int row, int kbyte) {
    return row * 256 + (kbyte ^ ((row & 7) << 4));
}

// ---------- prep: W[k][n] fp32 -> WT[n][k] bf16, 8 matrices ----------
__global__ __launch_bounds__(256) void prep_w(
    const float* __restrict__ W0, const float* __restrict__ W1,
    const float* __restrict__ W2, const float* __restrict__ W3,
    const float* __restrict__ W4, const float* __restrict__ W5,
    const float* __restrict__ W6, const float* __restrict__ W7,
    unsigned short* __restrict__ WTH)
{
    int g = blockIdx.x * 256 + threadIdx.x;          // 8*16384 threads
    int m = g >> 14, o = g & 16383;
    int n = o >> 7, k = o & 127;
    const float* W;
    switch (m) {
        case 0: W = W0; break; case 1: W = W1; break;
        case 2: W = W2; break; case 3: W = W3; break;
        case 4: W = W4; break; case 5: W = W5; break;
        case 6: W = W6; break; default: W = W7; break;
    }
    WTH[g] = f2bf(W[k * 128 + n]);
}

// ---------- GEMM via MFMA, bf16, B staged in LDS ----------
// A fp32 [nrows][128]; WT[4][n][k] bf16 for this layer. Grid: NWG 1D with
// bijective XCD swizzle; wgid&1 = output pair p (outs {0,1} or {2,3}).
// Block: 4 waves; wave w: output o=w&1 (of the pair), rows (w>>1)*32..+32.
// Outputs: O0=Q f32, O1=K bf16, O2=V bf16, O3=S f32.
__global__ __launch_bounds__(256, 2) void gemm_mfma(
    const float* __restrict__ A, int nrows,
    const unsigned short* __restrict__ WT,
    const float* __restrict__ b0, const float* __restrict__ b1,
    const float* __restrict__ b2, const float* __restrict__ b3,
    float* __restrict__ O0, unsigned short* __restrict__ O1,
    unsigned short* __restrict__ O2, float* __restrict__ O3)
{
    __shared__ unsigned short As[BM * 128];      // 16 KB, swizzled rows
    __shared__ unsigned short Bs[2 * 128 * 128]; // 64 KB, swizzled rows

    // bijective XCD-chunked swizzle (m204): NWG=1564, q=195, r=4
    const int orig = blockIdx.x;
    const int xcd = orig & 7, lid = orig >> 3;
    const int wgid = ((xcd < 4) ? xcd * 196 : 784 + (xcd - 4) * 195) + lid;
    const int xt = wgid >> 1;      // row tile
    const int p  = wgid & 1;       // output pair
    const int row0 = xt * BM;
    const int t = threadIdx.x;

    // ---- stage A: 64x128 fp32 -> bf16, 1024 8-float chunks ----
    #pragma unroll
    for (int i = 0; i < 4; ++i) {
        int chunk = t + i * 256;
        int row = chunk >> 4, c8 = chunk & 15;
        int gr = row0 + row;
        float4 a0, a1;
        if (gr < nrows) {
            a0 = *(const float4*)(A + (size_t)gr * 128 + c8 * 8);
            a1 = *(const float4*)(A + (size_t)gr * 128 + c8 * 8 + 4);
        } else {
            a0 = make_float4(0.f, 0.f, 0.f, 0.f);
            a1 = a0;
        }
        short8 h;
        h[0] = f2bf(a0.x); h[1] = f2bf(a0.y); h[2] = f2bf(a0.z); h[3] = f2bf(a0.w);
        h[4] = f2bf(a1.x); h[5] = f2bf(a1.y); h[6] = f2bf(a1.z); h[7] = f2bf(a1.w);
        *(short8*)((char*)As + swz(row, c8 * 16)) = h;
    }
    // ---- stage B: 2 outputs x 128x128 bf16, 4096 16B chunks ----
    #pragma unroll
    for (int i = 0; i < 16; ++i) {
        int chunk = t + i * 256;
        int o = chunk >> 11, n = (chunk >> 4) & 127, c8 = chunk & 15;
        short8 b = *(const short8*)(WT + ((size_t)(p * 2 + o) * 16384 + n * 128 + c8 * 8));
        *(short8*)((char*)Bs + o * 32768 + swz(n, c8 * 16)) = b;
    }
    __syncthreads();

    const int lane = t & 63;
    const int w    = t >> 6;
    const int o    = w & 1;         // which output of the pair
    const int rg2  = w >> 1;        // 32-row group (0/1)
    const int mi   = lane & 15;
    const int kg   = lane >> 4;     // 0..3

    f32x4 acc[2][8] = {};

    #pragma unroll
    for (int ks = 0; ks < 4; ++ks) {
        const int kb = ks * 64 + kg * 16;   // byte offset in row
        short8 a0 = *(const short8*)((char*)As + swz(rg2 * 32 + mi, kb));
        short8 a1 = *(const short8*)((char*)As + swz(rg2 * 32 + 16 + mi, kb));
        #pragma unroll
        for (int ct = 0; ct < 8; ++ct) {
            short8 b = *(const short8*)((char*)Bs + o * 32768 + swz(ct * 16 + mi, kb));
            acc[0][ct] = __builtin_amdgcn_mfma_f32_16x16x32_bf16(a0, b, acc[0][ct], 0, 0, 0);
            acc[1][ct] = __builtin_amdgcn_mfma_f32_16x16x32_bf16(a1, b, acc[1][ct], 0, 0, 0);
        }
    }

    // epilogue: C[row = rg2*32 + tile*16 + (lane>>4)*4 + r][col = ct*16 + mi]
    const int out = p * 2 + o;
    const float* bptr = (out == 0) ? b0 : (out == 1) ? b1 : (out == 2) ? b2 : b3;
    const int g2 = lane >> 4;
    #pragma unroll
    for (int ct = 0; ct < 8; ++ct) {
        int col = ct * 16 + mi;
        float bias_v = bptr[col];
        #pragma unroll
        for (int tile = 0; tile < 2; ++tile) {
            #pragma unroll
            for (int r = 0; r < 4; ++r) {
                int grow = row0 + rg2 * 32 + tile * 16 + g2 * 4 + r;
                if (grow < nrows) {
                    float val = acc[tile][ct][r] + bias_v;
                    size_t idx = (size_t)grow * 128 + col;
                    if (out == 0)      O0[idx] = val;
                    else if (out == 1) O1[idx] = f2bf(val);
                    else if (out == 2) O2[idx] = f2bf(val);
                    else               O3[idx] = val;
                }
            }
        }
    }
}

// ---------- CSR build ----------
__global__ __launch_bounds__(256) void hist_k(const int* __restrict__ dst, int* __restrict__ deg)
{
    int e = blockIdx.x * 256 + threadIdx.x;
    if (e >= N_EDGES) return;
    atomicAdd(&deg[dst[e]], 1);
}

__global__ __launch_bounds__(256) void scan1_k(const int* __restrict__ deg, int* __restrict__ bsum)
{
    __shared__ int s[256];
    int t = threadIdx.x;
    s[t] = deg[blockIdx.x * 256 + t];
    __syncthreads();
    for (int off = 128; off > 0; off >>= 1) {
        if (t < off) s[t] += s[t + off];
        __syncthreads();
    }
    if (t == 0) bsum[blockIdx.x] = s[0];
}

__global__ __launch_bounds__(256) void scan2_k(const int* __restrict__ bsum, int* __restrict__ boff,
                                               int* __restrict__ rowptr)
{
    __shared__ int s[256];
    int t = threadIdx.x;
    int v = (t < NSCAN) ? bsum[t] : 0;
    s[t] = v;
    __syncthreads();
    for (int off = 1; off < 256; off <<= 1) {
        int v2 = (t >= off) ? s[t - off] : 0;
        __syncthreads();
        s[t] += v2;
        __syncthreads();
    }
    if (t < NSCAN) boff[t] = s[t] - v;          // exclusive
    if (t == 0) rowptr[N_NODES] = N_EDGES;
}

__global__ __launch_bounds__(256) void scan3_k(const int* __restrict__ deg, const int* __restrict__ boff,
                                               int* __restrict__ rowptr, int* __restrict__ cursor)
{
    __shared__ int s[256];
    int t = threadIdx.x;
    int i = blockIdx.x * 256 + t;
    int d = deg[i];
    s[t] = d;
    __syncthreads();
    for (int off = 1; off < 256; off <<= 1) {
        int v2 = (t >= off) ? s[t - off] : 0;
        __syncthreads();
        s[t] += v2;
        __syncthreads();
    }
    if (i < N_NODES) {
        int val = boff[blockIdx.x] + s[t] - d;  // exclusive prefix
        rowptr[i] = val;
        cursor[i] = val;
    }
}

__global__ __launch_bounds__(256) void fill_k(
    const int* __restrict__ src, const int* __restrict__ dst,
    int* __restrict__ cursor, int* __restrict__ esrc)
{
    int e = blockIdx.x * 256 + threadIdx.x;
    if (e >= N_EDGES) return;
    int p = atomicAdd(&cursor[dst[e]], 1);
    esrc[p] = src[e];
}

// ---------- fused edge+softmax+aggregate: one wave per node, bf16 K/V gather ----------
template<int H>
__global__ __launch_bounds__(256) void fused_attn(
    const float* __restrict__ Qm, const unsigned short* __restrict__ Km,
    const unsigned short* __restrict__ Vm, const float* __restrict__ Sm,
    const int* __restrict__ rowptr, const int* __restrict__ esrc,
    float* __restrict__ out, float scale)
{
    const int n = blockIdx.x * 4 + (threadIdx.x >> 6);   // 4 nodes/block, 1 wave each
    const int c = threadIdx.x & 63;
    const int start = rowptr[n];
    const int cnt   = rowptr[n + 1] - start;
    float2 q2 = *(const float2*)(Qm + (size_t)n * 128 + 2 * c);
    q2.x *= scale; q2.y *= scale;
    float ax = 0.f, ay = 0.f, den = 0.f;
    for (int base = 0; base < cnt; base += 64) {
        int mm = min(64, cnt - base);
        int my_s = (c < mm) ? esrc[start + base + c] : 0;
        for (int j = 0; j < mm; ++j) {
            int s = __shfl(my_s, j);
            ushort2 kb = *(const ushort2*)(Km + (size_t)s * 128 + 2 * c);
            float p = bf2f(kb.x) * q2.x + bf2f(kb.y) * q2.y;
            if (H == 8) {
                p += __shfl_xor(p, 1);
                p += __shfl_xor(p, 2);
                p += __shfl_xor(p, 4);
            } else {
                #pragma unroll
                for (int o = 1; o < 64; o <<= 1) p += __shfl_xor(p, o);
            }
            float ea = __expf(p);
            ushort2 vb = *(const ushort2*)(Vm + (size_t)s * 128 + 2 * c);
            ax += ea * bf2f(vb.x);
            ay += ea * bf2f(vb.y);
            den += ea;
        }
    }
    float rd = 1.f / (den + 1e-16f);
    float2 s2 = *(const float2*)(Sm + (size_t)n * 128 + 2 * c);
    float2 o2; o2.x = ax * rd + s2.x; o2.y = ay * rd + s2.y;
    *(float2*)(out + (size_t)n * 128 + 2 * c) = o2;
}

// ---------- launch ----------
extern "C" void kernel_launch(void* const* d_in, const int* in_sizes, int n_in,
                              void* d_out, int out_size, void* d_ws, size_t ws_size,
                              hipStream_t stream)
{
    const float* x       = (const float*)d_in[0];
    const int*   ei      = (const int*)d_in[1];
    const int*   esrc_in = ei;                 // edge_index[0] = src
    const int*   edst_in = ei + N_EDGES;       // edge_index[1] = dst

    const float* Wq1 = (const float*)d_in[2];  const float* bq1 = (const float*)d_in[3];
    const float* Wk1 = (const float*)d_in[4];  const float* bk1 = (const float*)d_in[5];
    const float* Wv1 = (const float*)d_in[6];  const float* bv1 = (const float*)d_in[7];
    const float* Ws1 = (const float*)d_in[8];  const float* bs1 = (const float*)d_in[9];
    const float* Wq2 = (const float*)d_in[10]; const float* bq2 = (const float*)d_in[11];
    const float* Wk2 = (const float*)d_in[12]; const float* bk2 = (const float*)d_in[13];
    const float* Wv2 = (const float*)d_in[14]; const float* bv2 = (const float*)d_in[15];
    const float* Ws2 = (const float*)d_in[16]; const float* bs2 = (const float*)d_in[17];

    float* out = (float*)d_out;

    // workspace layout (bytes)
    char* base = (char*)d_ws;
    const size_t NF4 = (size_t)N_NODES * 128 * 4;   // 25.6 MB
    const size_t NF2 = (size_t)N_NODES * 128 * 2;   // 12.8 MB
    size_t off = 0;
    float*          Q    = (float*)(base + off);          off += NF4;
    float*          S    = (float*)(base + off);          off += NF4;
    unsigned short* Kb   = (unsigned short*)(base + off); off += NF2;
    unsigned short* Vb   = (unsigned short*)(base + off); off += NF2;
    unsigned short* WTH  = (unsigned short*)(base + off); off += 8 * 16384 * 2;
    int*            DEG  = (int*)(base + off);            off += (size_t)NP2 * 4;
    int*            ROW  = (int*)(base + off);            off += (size_t)NP2 * 4;
    int*            CUR  = (int*)(base + off);            off += (size_t)NP2 * 4;
    int*            BSUM = (int*)(base + off);            off += 1024;
    int*            BOFF = (int*)(base + off);            off += 1024;
    int*            ESRC = (int*)(base + off);            off += (size_t)N_EDGES * 4;
    if (ws_size < off) return;

    const int EB1 = (N_EDGES + 255) / 256;     // 4688
    const int FB  = N_NODES / 4;               // 12500

    hipMemsetAsync(DEG, 0, (size_t)NP2 * 4, stream);

    // weight prep (both layers): order Q1,K1,V1,S1,Q2,K2,V2,S2
    prep_w<<<512, 256, 0, stream>>>(Wq1, Wk1, Wv1, Ws1, Wq2, Wk2, Wv2, Ws2, WTH);

    // CSR by destination (shared by both layers)
    hist_k<<<EB1, 256, 0, stream>>>(edst_in, DEG);
    scan1_k<<<NSCAN, 256, 0, stream>>>(DEG, BSUM);
    scan2_k<<<1, 256, 0, stream>>>(BSUM, BOFF, ROW);
    scan3_k<<<NSCAN, 256, 0, stream>>>(DEG, BOFF, ROW, CUR);
    fill_k<<<EB1, 256, 0, stream>>>(esrc_in, edst_in, CUR, ESRC);

    // ---- layer 1: heads=8, ch=16 ----
    gemm_mfma<<<NWG, 256, 0, stream>>>(x, N_NODES, WTH,
        bq1, bk1, bv1, bs1, Q, Kb, Vb, S);
    fused_attn<8><<<FB, 256, 0, stream>>>(Q, Kb, Vb, S, ROW, ESRC, out, 0.25f);

    // ---- layer 2: heads=1, ch=128 ----
    gemm_mfma<<<NWG, 256, 0, stream>>>(out, N_NODES, WTH + 4 * 16384,
        bq2, bk2, bv2, bs2, Q, Kb, Vb, S);
    fused_attn<1><<<FB, 256, 0, stream>>>(Q, Kb, Vb, S, ROW, ESRC, out, 0.08838834764831845f);
}

// Round 9
// 551.569 us; speedup vs baseline: 2.4481x; 1.0872x over previous
//
#include <hip/hip_runtime.h>
#include <cstdint>

#define N_NODES 50000
#define N_EDGES 1200000
#define NP2 50176          // padded node count, multiple of 256, >= N_NODES+1
#define NSCAN 196          // NP2/256
#define BM 64              // rows per GEMM block
#define GT 782             // row tiles = ceil(50000/64)
#define NWG 1564           // GT*2 output-pairs

typedef __attribute__((ext_vector_type(8))) short short8;   // 8 bf16 in 4 VGPRs
typedef __attribute__((ext_vector_type(4))) float f32x4;

__device__ __forceinline__ unsigned short f2bf(float x) {
    unsigned u = __float_as_uint(x);
    unsigned r = (u + 0x7FFFu + ((u >> 16) & 1u)) >> 16;   // RNE
    return (unsigned short)r;
}
__device__ __forceinline__ float bf2f(unsigned short h) {
    return __uint_as_float(((unsigned)h) << 16);
}
// LDS byte offset for [row][128 bf16] tiles with bank-conflict XOR swizzle (T2)
__device__ __forceinline__ int swz(int row, int kbyte) {
    return row * 256 + (kbyte ^ ((row & 7) << 4));
}

// ---------- prep: W[k][n] fp32 -> WT[n][k] bf16, 8 matrices ----------
__global__ __launch_bounds__(256) void prep_w(
    const float* __restrict__ W0, const float* __restrict__ W1,
    const float* __restrict__ W2, const float* __restrict__ W3,
    const float* __restrict__ W4, const float* __restrict__ W5,
    const float* __restrict__ W6, const float* __restrict__ W7,
    unsigned short* __restrict__ WTH)
{
    int g = blockIdx.x * 256 + threadIdx.x;          // 8*16384 threads
    int m = g >> 14, o = g & 16383;
    int n = o >> 7, k = o & 127;
    const float* W;
    switch (m) {
        case 0: W = W0; break; case 1: W = W1; break;
        case 2: W = W2; break; case 3: W = W3; break;
        case 4: W = W4; break; case 5: W = W5; break;
        case 6: W = W6; break; default: W = W7; break;
    }
    WTH[g] = f2bf(W[k * 128 + n]);
}

// ---------- GEMM via MFMA, bf16, B staged in LDS ----------
__global__ __launch_bounds__(256, 2) void gemm_mfma(
    const float* __restrict__ A, int nrows,
    const unsigned short* __restrict__ WT,
    const float* __restrict__ b0, const float* __restrict__ b1,
    const float* __restrict__ b2, const float* __restrict__ b3,
    float* __restrict__ O0, unsigned short* __restrict__ O1,
    unsigned short* __restrict__ O2, float* __restrict__ O3)
{
    __shared__ unsigned short As[BM * 128];      // 16 KB, swizzled rows
    __shared__ unsigned short Bs[2 * 128 * 128]; // 64 KB, swizzled rows

    // bijective XCD-chunked swizzle (m204): NWG=1564, q=195, r=4
    const int orig = blockIdx.x;
    const int xcd = orig & 7, lid = orig >> 3;
    const int wgid = ((xcd < 4) ? xcd * 196 : 784 + (xcd - 4) * 195) + lid;
    const int xt = wgid >> 1;      // row tile
    const int p  = wgid & 1;       // output pair
    const int row0 = xt * BM;
    const int t = threadIdx.x;

    // ---- stage A: 64x128 fp32 -> bf16 ----
    #pragma unroll
    for (int i = 0; i < 4; ++i) {
        int chunk = t + i * 256;
        int row = chunk >> 4, c8 = chunk & 15;
        int gr = row0 + row;
        float4 a0, a1;
        if (gr < nrows) {
            a0 = *(const float4*)(A + (size_t)gr * 128 + c8 * 8);
            a1 = *(const float4*)(A + (size_t)gr * 128 + c8 * 8 + 4);
        } else {
            a0 = make_float4(0.f, 0.f, 0.f, 0.f);
            a1 = a0;
        }
        short8 h;
        h[0] = f2bf(a0.x); h[1] = f2bf(a0.y); h[2] = f2bf(a0.z); h[3] = f2bf(a0.w);
        h[4] = f2bf(a1.x); h[5] = f2bf(a1.y); h[6] = f2bf(a1.z); h[7] = f2bf(a1.w);
        *(short8*)((char*)As + swz(row, c8 * 16)) = h;
    }
    // ---- stage B: 2 outputs x 128x128 bf16 ----
    #pragma unroll
    for (int i = 0; i < 16; ++i) {
        int chunk = t + i * 256;
        int o = chunk >> 11, n = (chunk >> 4) & 127, c8 = chunk & 15;
        short8 b = *(const short8*)(WT + ((size_t)(p * 2 + o) * 16384 + n * 128 + c8 * 8));
        *(short8*)((char*)Bs + o * 32768 + swz(n, c8 * 16)) = b;
    }
    __syncthreads();

    const int lane = t & 63;
    const int w    = t >> 6;
    const int o    = w & 1;         // which output of the pair
    const int rg2  = w >> 1;        // 32-row group (0/1)
    const int mi   = lane & 15;
    const int kg   = lane >> 4;     // 0..3

    f32x4 acc[2][8] = {};

    #pragma unroll
    for (int ks = 0; ks < 4; ++ks) {
        const int kb = ks * 64 + kg * 16;   // byte offset in row
        short8 a0 = *(const short8*)((char*)As + swz(rg2 * 32 + mi, kb));
        short8 a1 = *(const short8*)((char*)As + swz(rg2 * 32 + 16 + mi, kb));
        #pragma unroll
        for (int ct = 0; ct < 8; ++ct) {
            short8 b = *(const short8*)((char*)Bs + o * 32768 + swz(ct * 16 + mi, kb));
            acc[0][ct] = __builtin_amdgcn_mfma_f32_16x16x32_bf16(a0, b, acc[0][ct], 0, 0, 0);
            acc[1][ct] = __builtin_amdgcn_mfma_f32_16x16x32_bf16(a1, b, acc[1][ct], 0, 0, 0);
        }
    }

    const int out = p * 2 + o;
    const float* bptr = (out == 0) ? b0 : (out == 1) ? b1 : (out == 2) ? b2 : b3;
    const int g2 = lane >> 4;
    #pragma unroll
    for (int ct = 0; ct < 8; ++ct) {
        int col = ct * 16 + mi;
        float bias_v = bptr[col];
        #pragma unroll
        for (int tile = 0; tile < 2; ++tile) {
            #pragma unroll
            for (int r = 0; r < 4; ++r) {
                int grow = row0 + rg2 * 32 + tile * 16 + g2 * 4 + r;
                if (grow < nrows) {
                    float val = acc[tile][ct][r] + bias_v;
                    size_t idx = (size_t)grow * 128 + col;
                    if (out == 0)      O0[idx] = val;
                    else if (out == 1) O1[idx] = f2bf(val);
                    else if (out == 2) O2[idx] = f2bf(val);
                    else               O3[idx] = val;
                }
            }
        }
    }
}

// ---------- CSR build ----------
__global__ __launch_bounds__(256) void hist_k(const int* __restrict__ dst, int* __restrict__ deg)
{
    int e = blockIdx.x * 256 + threadIdx.x;
    if (e >= N_EDGES) return;
    atomicAdd(&deg[dst[e]], 1);
}

__global__ __launch_bounds__(256) void scan1_k(const int* __restrict__ deg, int* __restrict__ bsum)
{
    __shared__ int s[256];
    int t = threadIdx.x;
    s[t] = deg[blockIdx.x * 256 + t];
    __syncthreads();
    for (int off = 128; off > 0; off >>= 1) {
        if (t < off) s[t] += s[t + off];
        __syncthreads();
    }
    if (t == 0) bsum[blockIdx.x] = s[0];
}

__global__ __launch_bounds__(256) void scan2_k(const int* __restrict__ bsum, int* __restrict__ boff,
                                               int* __restrict__ rowptr)
{
    __shared__ int s[256];
    int t = threadIdx.x;
    int v = (t < NSCAN) ? bsum[t] : 0;
    s[t] = v;
    __syncthreads();
    for (int off = 1; off < 256; off <<= 1) {
        int v2 = (t >= off) ? s[t - off] : 0;
        __syncthreads();
        s[t] += v2;
        __syncthreads();
    }
    if (t < NSCAN) boff[t] = s[t] - v;          // exclusive
    if (t == 0) rowptr[N_NODES] = N_EDGES;
}

__global__ __launch_bounds__(256) void scan3_k(const int* __restrict__ deg, const int* __restrict__ boff,
                                               int* __restrict__ rowptr, int* __restrict__ cursor)
{
    __shared__ int s[256];
    int t = threadIdx.x;
    int i = blockIdx.x * 256 + t;
    int d = deg[i];
    s[t] = d;
    __syncthreads();
    for (int off = 1; off < 256; off <<= 1) {
        int v2 = (t >= off) ? s[t - off] : 0;
        __syncthreads();
        s[t] += v2;
        __syncthreads();
    }
    if (i < N_NODES) {
        int val = boff[blockIdx.x] + s[t] - d;  // exclusive prefix
        rowptr[i] = val;
        cursor[i] = val;
    }
}

__global__ __launch_bounds__(256) void fill_k(
    const int* __restrict__ src, const int* __restrict__ dst,
    int* __restrict__ cursor, int* __restrict__ esrc)
{
    int e = blockIdx.x * 256 + threadIdx.x;
    if (e >= N_EDGES) return;
    int p = atomicAdd(&cursor[dst[e]], 1);
    esrc[p] = src[e];
}

// ---------- fused edge+softmax+aggregate v2: edge-per-lane-group ----------
// Wave per node. Lane l = (sub-edge i = l>>3, channel-block h = l&7).
// Per 8-edge chunk each lane loads 32B K-slice + 32B V-slice of ITS edge and
// computes the 16-ch dot in-lane. H==8: dot IS the head-h alpha. H==1: partial
// dot, combined by 3 shfl_xor (masks 1,2,4) across the 8 h-lanes of the edge.
// ea replicated across h-lanes is harmless: den is reduced only over i-strides.
// acc[16] + den per lane; ONE cross-lane reduce (masks 8,16,32) per node.
template<int H>
__global__ __launch_bounds__(256) void fused_attn(
    const float* __restrict__ Qm, const unsigned short* __restrict__ Km,
    const unsigned short* __restrict__ Vm, const float* __restrict__ Sm,
    const int* __restrict__ rowptr, const int* __restrict__ esrc,
    float* __restrict__ out, float scale)
{
    const int n = blockIdx.x * 4 + (threadIdx.x >> 6);   // 4 nodes/block, 1 wave each
    const int l = threadIdx.x & 63;
    const int i = l >> 3;                                 // sub-edge 0..7
    const int h = l & 7;                                  // channel block 0..7
    const int start = rowptr[n];
    const int cnt   = rowptr[n + 1] - start;

    float q[16];
    {
        const float4* qp = (const float4*)(Qm + (size_t)n * 128 + h * 16);
        #pragma unroll
        for (int r = 0; r < 4; ++r) {
            float4 v = qp[r];
            q[4*r+0] = v.x * scale; q[4*r+1] = v.y * scale;
            q[4*r+2] = v.z * scale; q[4*r+3] = v.w * scale;
        }
    }

    float acc[16];
    #pragma unroll
    for (int c = 0; c < 16; ++c) acc[c] = 0.f;
    float den = 0.f;

    for (int base = 0; base < cnt; base += 8) {
        const int ei = base + i;
        const bool valid = ei < cnt;
        const int s = esrc[start + (valid ? ei : 0)];
        const short8* kp = (const short8*)(Km + (size_t)s * 128 + h * 16);
        short8 k0 = kp[0], k1 = kp[1];
        const short8* vp = (const short8*)(Vm + (size_t)s * 128 + h * 16);
        short8 v0 = vp[0], v1 = vp[1];

        float d0 = 0.f, d1 = 0.f;           // two chains for ILP
        #pragma unroll
        for (int c = 0; c < 8; ++c) {
            d0 += bf2f((unsigned short)k0[c]) * q[c];
            d1 += bf2f((unsigned short)k1[c]) * q[8 + c];
        }
        float d = d0 + d1;
        if (H == 1) {                       // combine partials across h-lanes
            d += __shfl_xor(d, 1);
            d += __shfl_xor(d, 2);
            d += __shfl_xor(d, 4);
        }
        float ea = valid ? __expf(d) : 0.f;
        den += ea;
        #pragma unroll
        for (int c = 0; c < 8; ++c) {
            acc[c]     += ea * bf2f((unsigned short)v0[c]);
            acc[8 + c] += ea * bf2f((unsigned short)v1[c]);
        }
    }

    // reduce over sub-edge lanes (i): XOR masks 8,16,32
    #pragma unroll
    for (int m = 8; m <= 32; m <<= 1) {
        den += __shfl_xor(den, m);
        #pragma unroll
        for (int c = 0; c < 16; ++c) acc[c] += __shfl_xor(acc[c], m);
    }

    if (l < 8) {                            // i==0 lanes, h==l: write channels [16h,16h+16)
        float rd = 1.f / (den + 1e-16f);
        const float4* sp = (const float4*)(Sm + (size_t)n * 128 + l * 16);
        float4*       op = (float4*)(out + (size_t)n * 128 + l * 16);
        #pragma unroll
        for (int r = 0; r < 4; ++r) {
            float4 sv = sp[r];
            float4 ov;
            ov.x = acc[4*r+0] * rd + sv.x;
            ov.y = acc[4*r+1] * rd + sv.y;
            ov.z = acc[4*r+2] * rd + sv.z;
            ov.w = acc[4*r+3] * rd + sv.w;
            op[r] = ov;
        }
    }
}

// ---------- launch ----------
extern "C" void kernel_launch(void* const* d_in, const int* in_sizes, int n_in,
                              void* d_out, int out_size, void* d_ws, size_t ws_size,
                              hipStream_t stream)
{
    const float* x       = (const float*)d_in[0];
    const int*   ei      = (const int*)d_in[1];
    const int*   esrc_in = ei;                 // edge_index[0] = src
    const int*   edst_in = ei + N_EDGES;       // edge_index[1] = dst

    const float* Wq1 = (const float*)d_in[2];  const float* bq1 = (const float*)d_in[3];
    const float* Wk1 = (const float*)d_in[4];  const float* bk1 = (const float*)d_in[5];
    const float* Wv1 = (const float*)d_in[6];  const float* bv1 = (const float*)d_in[7];
    const float* Ws1 = (const float*)d_in[8];  const float* bs1 = (const float*)d_in[9];
    const float* Wq2 = (const float*)d_in[10]; const float* bq2 = (const float*)d_in[11];
    const float* Wk2 = (const float*)d_in[12]; const float* bk2 = (const float*)d_in[13];
    const float* Wv2 = (const float*)d_in[14]; const float* bv2 = (const float*)d_in[15];
    const float* Ws2 = (const float*)d_in[16]; const float* bs2 = (const float*)d_in[17];

    float* out = (float*)d_out;

    // workspace layout (bytes)
    char* base = (char*)d_ws;
    const size_t NF4 = (size_t)N_NODES * 128 * 4;   // 25.6 MB
    const size_t NF2 = (size_t)N_NODES * 128 * 2;   // 12.8 MB
    size_t off = 0;
    float*          Q    = (float*)(base + off);          off += NF4;
    float*          S    = (float*)(base + off);          off += NF4;
    unsigned short* Kb   = (unsigned short*)(base + off); off += NF2;
    unsigned short* Vb   = (unsigned short*)(base + off); off += NF2;
    unsigned short* WTH  = (unsigned short*)(base + off); off += 8 * 16384 * 2;
    int*            DEG  = (int*)(base + off);            off += (size_t)NP2 * 4;
    int*            ROW  = (int*)(base + off);            off += (size_t)NP2 * 4;
    int*            CUR  = (int*)(base + off);            off += (size_t)NP2 * 4;
    int*            BSUM = (int*)(base + off);            off += 1024;
    int*            BOFF = (int*)(base + off);            off += 1024;
    int*            ESRC = (int*)(base + off);            off += (size_t)N_EDGES * 4;
    if (ws_size < off) return;

    const int EB1 = (N_EDGES + 255) / 256;     // 4688
    const int FB  = N_NODES / 4;               // 12500

    hipMemsetAsync(DEG, 0, (size_t)NP2 * 4, stream);

    // weight prep (both layers): order Q1,K1,V1,S1,Q2,K2,V2,S2
    prep_w<<<512, 256, 0, stream>>>(Wq1, Wk1, Wv1, Ws1, Wq2, Wk2, Wv2, Ws2, WTH);

    // CSR by destination (shared by both layers)
    hist_k<<<EB1, 256, 0, stream>>>(edst_in, DEG);
    scan1_k<<<NSCAN, 256, 0, stream>>>(DEG, BSUM);
    scan2_k<<<1, 256, 0, stream>>>(BSUM, BOFF, ROW);
    scan3_k<<<NSCAN, 256, 0, stream>>>(DEG, BOFF, ROW, CUR);
    fill_k<<<EB1, 256, 0, stream>>>(esrc_in, edst_in, CUR, ESRC);

    // ---- layer 1: heads=8, ch=16 ----
    gemm_mfma<<<NWG, 256, 0, stream>>>(x, N_NODES, WTH,
        bq1, bk1, bv1, bs1, Q, Kb, Vb, S);
    fused_attn<8><<<FB, 256, 0, stream>>>(Q, Kb, Vb, S, ROW, ESRC, out, 0.25f);

    // ---- layer 2: heads=1, ch=128 ----
    gemm_mfma<<<NWG, 256, 0, stream>>>(out, N_NODES, WTH + 4 * 16384,
        bq2, bk2, bv2, bs2, Q, Kb, Vb, S);
    fused_attn<1><<<FB, 256, 0, stream>>>(Q, Kb, Vb, S, ROW, ESRC, out, 0.08838834764831845f);
}